// Round 10
// baseline (62.536 us; speedup 1.0000x reference)
//
#include <hip/hip_runtime.h>
#include <hip/hip_bf16.h>
#include <math.h>

typedef _Float16 half8  __attribute__((ext_vector_type(8)));
typedef _Float16 half4v __attribute__((ext_vector_type(4)));
typedef __fp16   fp16x2 __attribute__((ext_vector_type(2)));
typedef float    f32x4  __attribute__((ext_vector_type(4)));
typedef float    f32x16 __attribute__((ext_vector_type(16)));
typedef int      i32x2v __attribute__((ext_vector_type(2)));

#define DDIM 128
#define LQ   512
#define NKV  2048
#define NB   32
#define NIT  8

union U32H2 { unsigned u; fp16x2 h; };
union PW    { unsigned u[4]; half8 h; };

// permlane32_swap(a,b) -> ([a_lo|b_lo], [a_hi|b_hi])
__device__ __forceinline__ float xmax64(float v) {
  i32x2v r = __builtin_amdgcn_permlane32_swap(__float_as_int(v), __float_as_int(v), false, false);
  return fmaxf(__int_as_float(r[0]), __int_as_float(r[1]));
}
__device__ __forceinline__ float xsum64(float v) {
  i32x2v r = __builtin_amdgcn_permlane32_swap(__float_as_int(v), __float_as_int(v), false, false);
  return __int_as_float(r[0]) + __int_as_float(r[1]);
}

// ---------------- prep: fism f32 -> fragment-major KF and VF (f16) ----------------
// KF chunk (16KB): unit (ns*8+c)*64 + hi*32 + l31 holds K[ns*32+l31][c*16+hi*8 ..+8]
// VF chunk (16KB): unit (dt*4+kb)*64 + hi*32 + l31 holds V[kb*16+hi*8 ..+8][dt*32+l31]
__global__ __launch_bounds__(256)
void prep(const float* __restrict__ fism, _Float16* __restrict__ KF,
          _Float16* __restrict__ VF)
{
  __shared__ _Float16 T[64 * DDIM];  // [d][64 kv], swizzled 16B units
  const int tid = threadIdx.x;
  const int bb  = blockIdx.x >> 5;
  const int idx = blockIdx.x & 31;
  const int kv0 = idx * 64;
  {
    const int r  = tid >> 2;       // kv row in chunk
    const int cq = tid & 3;        // 32-d quarter
    const float* src = fism + ((size_t)(bb*NKV + kv0 + r) * DDIM + cq*32);
    float4 v[8];
    #pragma unroll
    for (int k = 0; k < 8; ++k) v[k] = ((const float4*)src)[k];
    _Float16 h[32];
    #pragma unroll
    for (int k = 0; k < 8; ++k) {
      h[4*k+0] = (_Float16)v[k].x; h[4*k+1] = (_Float16)v[k].y;
      h[4*k+2] = (_Float16)v[k].z; h[4*k+3] = (_Float16)v[k].w;
    }
    // KF direct stores
    const size_t kfb = (size_t)(bb*32 + idx) * 8192;
    const int ns = r >> 5, l31r = r & 31;
    #pragma unroll
    for (int g = 0; g < 4; ++g) {
      const int c   = cq*2 + (g >> 1);
      const int hig = g & 1;
      const int unit = (ns*8 + c)*64 + hig*32 + l31r;
      *(half8*)&KF[kfb + (size_t)unit*8] = *(half8*)&h[(g>>1)*16 + hig*8];
    }
    // T for V transpose
    #pragma unroll
    for (int j = 0; j < 32; ++j) {
      const int d = cq*32 + j;
      T[d*64 + (((r>>3) ^ (d&7))<<3) + (r&7)] = h[j];
    }
  }
  __syncthreads();
  {
    const size_t vfb = (size_t)(bb*32 + idx) * 8192;
    #pragma unroll
    for (int j = 0; j < 4; ++j) {
      const int u  = tid*4 + j;
      const int dt = u >> 8, kb = (u >> 6) & 3, l = u & 63;
      const int d  = dt*32 + (l & 31);
      const int kv8 = kb*2 + (l >> 5);
      *(half8*)&VF[vfb + (size_t)u*8] = *(half8*)&T[d*64 + ((kv8 ^ (d & 7)) << 3)];
    }
  }
}

// ---------------- main: barrier-free loop, direct-to-reg fragments ----------------
__global__ __launch_bounds__(256, 2)
void gattn(const float* __restrict__ seq, const _Float16* __restrict__ KF,
           const _Float16* __restrict__ VF, float* __restrict__ out)
{
  __shared__ __align__(16) unsigned char POOL[49152]; // Q [0,8K) in loop; spills after
  __shared__ float stats[4][32][4];

  const int tid  = threadIdx.x;
  const int lane = tid & 63;
  const int kvh  = tid >> 6;      // wave = KV quarter 0..3
  const int l31  = lane & 31;
  const int hi   = lane >> 5;

  const int swzb = (blockIdx.x & 7) * 64 + (blockIdx.x >> 3);  // 512 blocks, bijective
  const int b    = swzb >> 4;
  const int qb   = (swzb & 15) * 32;

  const float* seqB = seq + (size_t)b * LQ * DDIM;
  float*       outB = out + (size_t)b * LQ * DDIM;

  // ---- Q -> LDS, fragment-major: unit c*64 + hi*32 + l31 = Q[l31][c*16+hi*8 ..+8] ----
  #pragma unroll
  for (int j = 0; j < 2; ++j) {
    const int u = tid*2 + j;
    const int c = u >> 6, l = u & 63;
    const float* qs = seqB + (size_t)(qb + (l & 31)) * DDIM + c*16 + (l >> 5)*8;
    float4 a  = ((const float4*)qs)[0];
    float4 b2 = ((const float4*)qs)[1];
    _Float16 hq[8];
    hq[0]=(_Float16)a.x;  hq[1]=(_Float16)a.y;  hq[2]=(_Float16)a.z;  hq[3]=(_Float16)a.w;
    hq[4]=(_Float16)b2.x; hq[5]=(_Float16)b2.y; hq[6]=(_Float16)b2.z; hq[7]=(_Float16)b2.w;
    *(half8*)&POOL[u*16] = *(half8*)hq;
  }
  __syncthreads();

  const int cb = b*32 + kvh*8;   // this wave's first chunk

  f32x16 acc[4];
  #pragma unroll
  for (int dt = 0; dt < 4; ++dt)
    #pragma unroll
    for (int i = 0; i < 16; ++i) acc[dt][i] = 0.f;

  float m_run = -INFINITY, tmax = -INFINITY, S_run = 0.f;

  half8 kf[16], vfr0[8], vfr1[8];
  {
    const _Float16* KFc = KF + (size_t)cb * 8192;
    #pragma unroll
    for (int i = 0; i < 16; ++i) kf[i] = *(const half8*)(KFc + (size_t)(i*64 + lane)*8);
  }

  #pragma unroll
  for (int t = 0; t < NIT; ++t) {
    const _Float16* VFc = VF + (size_t)(cb + t) * 8192;
    #pragma unroll
    for (int i = 0; i < 8; ++i) vfr0[i] = *(const half8*)(VFc + (size_t)(i*64 + lane)*8);

    half8 qa[8];
    #pragma unroll
    for (int c = 0; c < 8; ++c) qa[c] = *(const half8*)&POOL[(c*64 + lane)*16];

    // ---- QK^T: A=K (m=kv), B=Q (col=q=l31). sv[ns]: row=kv, col=q ----
    f32x16 sv[2];
    __builtin_amdgcn_s_setprio(1);
    #pragma unroll
    for (int ns = 0; ns < 2; ++ns) {
      f32x16 x;
      #pragma unroll
      for (int i = 0; i < 16; ++i) x[i] = 0.f;
      #pragma unroll
      for (int c = 0; c < 8; ++c)
        x = __builtin_amdgcn_mfma_f32_32x32x16_f16(kf[ns*8+c], qa[c], x, 0, 0, 0);
      sv[ns] = x;
    }
    __builtin_amdgcn_s_setprio(0);

    // pipeline: next K into same regs (WAR keeps it after QK), rest of V
    if (t + 1 < NIT) {
      const _Float16* KFn = KF + (size_t)(cb + t + 1) * 8192;
      #pragma unroll
      for (int i = 0; i < 16; ++i) kf[i] = *(const half8*)(KFn + (size_t)(i*64 + lane)*8);
    }
    #pragma unroll
    for (int i = 0; i < 8; ++i) vfr1[i] = *(const half8*)(VFc + (size_t)((8+i)*64 + lane)*8);

    // ---- online power-softmax (lane-local, col=q) ----
    float mx[16];
    #pragma unroll
    for (int i = 0; i < 16; ++i) mx[i] = fmaxf(sv[0][i], sv[1][i]);
    #pragma unroll
    for (int st = 8; st > 0; st >>= 1)
      #pragma unroll
      for (int i = 0; i < st; ++i) mx[i] = fmaxf(mx[i], mx[i+st]);
    const float cmax = xmax64(mx[0]);
    tmax = fmaxf(tmax, cmax);
    if (__any(cmax > m_run + 8.f)) {
      const float mn = fmaxf(m_run, cmax);
      const float sc = __expf(m_run - mn);
      S_run *= sc;
      m_run = mn;
      #pragma unroll
      for (int dt = 0; dt < 4; ++dt) acc[dt] *= sc;
    }
    float ts[16];
    #pragma unroll
    for (int i = 0; i < 16; ++i) {
      const float p0 = __expf(sv[0][i] - m_run);
      const float p1 = __expf(sv[1][i] - m_run);
      sv[0][i] = p0; sv[1][i] = p1;
      ts[i] = p0 + p1;
    }
    #pragma unroll
    for (int st = 8; st > 0; st >>= 1)
      #pragma unroll
      for (int i = 0; i < st; ++i) ts[i] += ts[i+st];
    S_run += xsum64(ts[0]);

    // ---- P pack + permlane redistribute (T12, r7-verified) ----
    PW pw[4];
    #pragma unroll
    for (int nss = 0; nss < 2; ++nss)
      #pragma unroll
      for (int b0 = 0; b0 < 2; ++b0) {
        U32H2 t0, t1, t2, t3;
        t0.h = __builtin_amdgcn_cvt_pkrtz(sv[nss][8*b0+0], sv[nss][8*b0+1]);
        t1.h = __builtin_amdgcn_cvt_pkrtz(sv[nss][8*b0+2], sv[nss][8*b0+3]);
        t2.h = __builtin_amdgcn_cvt_pkrtz(sv[nss][8*b0+4], sv[nss][8*b0+5]);
        t3.h = __builtin_amdgcn_cvt_pkrtz(sv[nss][8*b0+6], sv[nss][8*b0+7]);
        i32x2v r0 = __builtin_amdgcn_permlane32_swap((int)t0.u, (int)t2.u, false, false);
        i32x2v r1 = __builtin_amdgcn_permlane32_swap((int)t1.u, (int)t3.u, false, false);
        const int kb = 2*nss + b0;
        pw[kb].u[0] = (unsigned)r0[0];
        pw[kb].u[1] = (unsigned)r1[0];
        pw[kb].u[2] = (unsigned)r0[1];
        pw[kb].u[3] = (unsigned)r1[1];
      }

    // ---- PV^T: A=V^T (m=d), B=P (col=q). acc[dt]: row=d, col=q ----
    __builtin_amdgcn_s_setprio(1);
    #pragma unroll
    for (int dt = 0; dt < 4; ++dt) {
      #pragma unroll
      for (int kb = 0; kb < 4; ++kb) {
        const half8 v = (dt < 2) ? vfr0[dt*4 + kb] : vfr1[(dt-2)*4 + kb];
        acc[dt] = __builtin_amdgcn_mfma_f32_32x32x16_f16(v, pw[kb].h, acc[dt], 0, 0, 0);
      }
    }
    __builtin_amdgcn_s_setprio(0);
  }

  // ---- 4-way exact combine (waves 1..3 spill; wave 0 merges + epilogue) ----
  __syncthreads();
  if (kvh != 0) {
    float* base = (float*)&POOL[(kvh - 1) * 16384];
    #pragma unroll
    for (int dt = 0; dt < 4; ++dt)
      #pragma unroll
      for (int rg = 0; rg < 4; ++rg) {
        const int j = dt*4 + rg;
        f32x4 v = {acc[dt][4*rg+0], acc[dt][4*rg+1], acc[dt][4*rg+2], acc[dt][4*rg+3]};
        *(f32x4*)&base[lane*64 + ((j ^ (lane & 15)) << 2)] = v;
      }
    if (lane < 32) {
      stats[kvh][lane][0] = m_run;
      stats[kvh][lane][1] = S_run;
      stats[kvh][lane][2] = tmax;
    }
  }
  __syncthreads();

  if (kvh == 0) {
    float mj[4], Sj[4], tj[4];
    mj[0] = m_run; Sj[0] = S_run; tj[0] = tmax;
    #pragma unroll
    for (int j = 1; j < 4; ++j) {
      mj[j] = stats[j][l31][0];
      Sj[j] = stats[j][l31][1];
      tj[j] = stats[j][l31][2];
    }
    const float M = fmaxf(fmaxf(mj[0], mj[1]), fmaxf(mj[2], mj[3]));
    const float T = fmaxf(fmaxf(tj[0], tj[1]), fmaxf(tj[2], tj[3]));
    float ej[4], den = 0.f;
    #pragma unroll
    for (int j = 0; j < 4; ++j) { ej[j] = __expf(mj[j] - M); den += ej[j] * Sj[j]; }
    const float fs = __expf(0.5f * (M - T)) * rsqrtf(den);
    #pragma unroll
    for (int j = 0; j < 4; ++j) ej[j] *= fs;   // per-lane scalars (col=q)

    const int qrw = qb + l31;
    #pragma unroll
    for (int dt = 0; dt < 4; ++dt) {
      #pragma unroll
      for (int rg = 0; rg < 4; ++rg) {
        const int jj = dt*4 + rg;
        f32x4 av;
        #pragma unroll
        for (int i = 0; i < 4; ++i) av[i] = acc[dt][4*rg+i] * ej[0];
        #pragma unroll
        for (int j = 1; j < 4; ++j) {
          const float* base = (const float*)&POOL[(j - 1) * 16384];
          const f32x4 pj = *(const f32x4*)&base[lane*64 + ((jj ^ (lane & 15)) << 2)];
          av += pj * ej[j];
        }
        const int d0 = dt*32 + rg*8 + hi*4;
        const float4 s = *(const float4*)&seqB[(size_t)qrw * DDIM + d0];
        float4 o;
        o.x = 0.5f * s.x * (1.f + av[0]);
        o.y = 0.5f * s.y * (1.f + av[1]);
        o.z = 0.5f * s.z * (1.f + av[2]);
        o.w = 0.5f * s.w * (1.f + av[3]);
        *(float4*)&outB[(size_t)qrw * DDIM + d0] = o;
      }
    }
  }
}

// ---------------- fallback (r7, proven): used if ws too small ----------------
__global__ __launch_bounds__(512, 2)
void gattn_fb(const float* __restrict__ seq, const float* __restrict__ fism,
              float* __restrict__ out)
{
  const int tid  = threadIdx.x;
  const int lane = tid & 63;
  const int wv   = tid >> 6;
  const int wq   = wv & 1;
  const int kvq  = wv >> 1;
  const int l31  = lane & 31;
  const int hi   = lane >> 5;

  const int swz = (blockIdx.x & 7) * 32 + (blockIdx.x >> 3);
  const int b   = swz >> 3;
  const int qb  = (swz & 7) * 64;

  const float* seqB = seq  + (size_t)b * LQ * DDIM;
  const float* fisB = fism + (size_t)b * NKV * DDIM;
  float*       outB = out  + (size_t)b * LQ * DDIM;

  __shared__ _Float16 Ksh[4][64 * DDIM];
  __shared__ _Float16 VTsh[4][(DDIM/2) * 128];
  __shared__ float    stats[4][2][32][3];

  half8 qf[8];
  {
    const int qrow = qb + wq * 32 + l31;
    #pragma unroll
    for (int c = 0; c < 8; ++c) {
      const float* p = seqB + (size_t)qrow * DDIM + c * 16 + hi * 8;
      float4 a  = *(const float4*)p;
      float4 b2 = *(const float4*)(p + 4);
      half8 h;
      h[0]=(_Float16)a.x;  h[1]=(_Float16)a.y;  h[2]=(_Float16)a.z;  h[3]=(_Float16)a.w;
      h[4]=(_Float16)b2.x; h[5]=(_Float16)b2.y; h[6]=(_Float16)b2.z; h[7]=(_Float16)b2.w;
      qf[c] = h;
    }
  }

  const int sp   = tid >> 3;
  const int dgrp = tid & 7;
  const int qstg = sp >> 4;
  const int spc  = sp & 15;

  f32x16 acc[4];
  #pragma unroll
  for (int dt = 0; dt < 4; ++dt)
    #pragma unroll
    for (int i = 0; i < 16; ++i) acc[dt][i] = 0.f;

  float m_run = -INFINITY, tmax = -INFINITY, S_run = 0.f;

  auto write_stage = [&](const float4* v) {
    #pragma unroll
    for (int r = 0; r < 4; ++r) {
      const int row = 4*spc + r;
      #pragma unroll
      for (int hh = 0; hh < 2; ++hh) {
        const float4 x = v[r*4 + hh*2];
        const float4 y = v[r*4 + hh*2 + 1];
        half8 h;
        h[0]=(_Float16)x.x; h[1]=(_Float16)x.y; h[2]=(_Float16)x.z; h[3]=(_Float16)x.w;
        h[4]=(_Float16)y.x; h[5]=(_Float16)y.y; h[6]=(_Float16)y.z; h[7]=(_Float16)y.w;
        const int idx = row*DDIM + ((dgrp*16 + hh*8) ^ (8*(row & 15)));
        *(half8*)&Ksh[qstg][idx] = h;
      }
    }
    #pragma unroll
    for (int k = 0; k < 16; ++k) {
      const int d = dgrp*16 + k;
      const int dRow = d >> 1, dSub = d & 1;
      half4v pk;
      #pragma unroll
      for (int r = 0; r < 4; ++r)
        pk[r] = (_Float16)(((const float*)&v[r*4 + (k>>2)])[k&3]);
      const int idx = dRow*128 + ((dSub*64 + 4*spc) ^ (8*(dRow & 15)));
      *(half4v*)&VTsh[qstg][idx] = pk;
    }
  };

  auto load_glb = [&](float4* v, int t) {
    const float* src = fisB + (size_t)(qstg*(NKV/4) + t*64) * DDIM;
    #pragma unroll
    for (int r = 0; r < 4; ++r)
      #pragma unroll
      for (int k = 0; k < 4; ++k)
        v[r*4+k] = *(const float4*)(src + (size_t)(4*spc + r)*DDIM + dgrp*16 + k*4);
  };

  {
    float4 stg[16];
    load_glb(stg, 0);
    write_stage(stg);
  }

  for (int t = 0; t < 8; ++t) {
    __syncthreads();
    float4 nxt[16];
    const bool have = (t + 1 < 8);
    if (have) load_glb(nxt, t + 1);

    f32x16 sv[2];
    #pragma unroll
    for (int nss = 0; nss < 2; ++nss) {
      f32x16 x;
      #pragma unroll
      for (int i = 0; i < 16; ++i) x[i] = 0.f;
      const int row = nss*32 + l31;
      const int sw  = 8*(row & 15);
      #pragma unroll
      for (int c = 0; c < 8; ++c) {
        const int idx = row*DDIM + ((c*16 + hi*8) ^ sw);
        half8 kf = *(const half8*)&Ksh[kvq][idx];
        x = __builtin_amdgcn_mfma_f32_32x32x16_f16(kf, qf[c], x, 0, 0, 0);
      }
      sv[nss] = x;
    }

    float mx[16];
    #pragma unroll
    for (int i = 0; i < 16; ++i) mx[i] = fmaxf(sv[0][i], sv[1][i]);
    #pragma unroll
    for (int st = 8; st > 0; st >>= 1)
      #pragma unroll
      for (int i = 0; i < st; ++i) mx[i] = fmaxf(mx[i], mx[i+st]);
    const float cmax = xmax64(mx[0]);
    tmax = fmaxf(tmax, cmax);
    if (__any(cmax > m_run + 8.f)) {
      const float mn = fmaxf(m_run, cmax);
      const float sc = __expf(m_run - mn);
      S_run *= sc;
      m_run = mn;
      #pragma unroll
      for (int dt = 0; dt < 4; ++dt) acc[dt] *= sc;
    }
    float ts[16];
    #pragma unroll
    for (int i = 0; i < 16; ++i) {
      const float p0 = __expf(sv[0][i] - m_run);
      const float p1 = __expf(sv[1][i] - m_run);
      sv[0][i] = p0; sv[1][i] = p1;
      ts[i] = p0 + p1;
    }
    #pragma unroll
    for (int st = 8; st > 0; st >>= 1)
      #pragma unroll
      for (int i = 0; i < st; ++i) ts[i] += ts[i+st];
    S_run += xsum64(ts[0]);

    PW pw[4];
    #pragma unroll
    for (int nss = 0; nss < 2; ++nss)
      #pragma unroll
      for (int b0 = 0; b0 < 2; ++b0) {
        U32H2 t0, t1, t2, t3;
        t0.h = __builtin_amdgcn_cvt_pkrtz(sv[nss][8*b0+0], sv[nss][8*b0+1]);
        t1.h = __builtin_amdgcn_cvt_pkrtz(sv[nss][8*b0+2], sv[nss][8*b0+3]);
        t2.h = __builtin_amdgcn_cvt_pkrtz(sv[nss][8*b0+4], sv[nss][8*b0+5]);
        t3.h = __builtin_amdgcn_cvt_pkrtz(sv[nss][8*b0+6], sv[nss][8*b0+7]);
        i32x2v r0 = __builtin_amdgcn_permlane32_swap((int)t0.u, (int)t2.u, false, false);
        i32x2v r1 = __builtin_amdgcn_permlane32_swap((int)t1.u, (int)t3.u, false, false);
        const int kb = 2*nss + b0;
        pw[kb].u[0] = (unsigned)r0[0];
        pw[kb].u[1] = (unsigned)r1[0];
        pw[kb].u[2] = (unsigned)r0[1];
        pw[kb].u[3] = (unsigned)r1[1];
      }

    #pragma unroll
    for (int dt = 0; dt < 4; ++dt) {
      const int d    = dt*32 + l31;
      const int dRow = d >> 1, dSub = d & 1;
      const int sw   = 8*(dRow & 15);
      #pragma unroll
      for (int kb = 0; kb < 4; ++kb) {
        const int idx = dRow*128 + ((dSub*64 + kb*16 + hi*8) ^ sw);
        half8 vtf = *(const half8*)&VTsh[kvq][idx];
        acc[dt] = __builtin_amdgcn_mfma_f32_32x32x16_f16(vtf, pw[kb].h, acc[dt], 0, 0, 0);
      }
    }

    __syncthreads();
    if (have) write_stage(nxt);
  }

  __syncthreads();

  float* Kf  = (float*)&Ksh[0][0];
  float* VTf = (float*)&VTsh[0][0];
  if (kvq != 0) {
    const int rgn = (kvq - 1) * 2 + wq;
    float* base = (rgn < 4) ? (Kf + rgn * 4096) : (VTf + (rgn - 4) * 4096);
    #pragma unroll
    for (int dt = 0; dt < 4; ++dt)
      #pragma unroll
      for (int rg = 0; rg < 4; ++rg) {
        f32x4 v = {acc[dt][4*rg+0], acc[dt][4*rg+1], acc[dt][4*rg+2], acc[dt][4*rg+3]};
        *(f32x4*)&base[lane*64 + (((dt*4+rg) ^ (lane & 15)) * 4)] = v;
      }
    if (lane < 32) {
      stats[kvq][wq][lane][0] = m_run;
      stats[kvq][wq][lane][1] = S_run;
      stats[kvq][wq][lane][2] = tmax;
    }
  }
  __syncthreads();

  if (kvq == 0) {
    float mj[4], Sj[4], tj[4];
    mj[0] = m_run; Sj[0] = S_run; tj[0] = tmax;
    #pragma unroll
    for (int j = 1; j < 4; ++j) {
      mj[j] = stats[j][wq][l31][0];
      Sj[j] = stats[j][wq][l31][1];
      tj[j] = stats[j][wq][l31][2];
    }
    const float M = fmaxf(fmaxf(tj[0], tj[1]), fmaxf(tj[2], tj[3]));
    float fj[4], den = 0.f;
    #pragma unroll
    for (int j = 0; j < 4; ++j) { fj[j] = __expf(mj[j] - M); den += fj[j] * Sj[j]; }
    const float rs = rsqrtf(den);
    #pragma unroll
    for (int j = 0; j < 4; ++j) fj[j] *= rs;

    const int qrow = qb + wq*32 + l31;
    #pragma unroll
    for (int dt = 0; dt < 4; ++dt) {
      #pragma unroll
      for (int rg = 0; rg < 4; ++rg) {
        f32x4 av = {acc[dt][4*rg+0], acc[dt][4*rg+1], acc[dt][4*rg+2], acc[dt][4*rg+3]};
        av *= fj[0];
        #pragma unroll
        for (int j = 1; j < 4; ++j) {
          const int rgn = (j - 1) * 2 + wq;
          const float* base = (rgn < 4) ? (Kf + rgn * 4096) : (VTf + (rgn - 4) * 4096);
          const f32x4 pj = *(const f32x4*)&base[lane*64 + (((dt*4+rg) ^ (lane & 15)) * 4)];
          av += pj * fj[j];
        }
        const int d0 = dt*32 + rg*8 + hi*4;
        const float4 s = *(const float4*)&seqB[(size_t)qrow * DDIM + d0];
        float4 o;
        o.x = 0.5f * s.x * (1.f + av[0]);
        o.y = 0.5f * s.y * (1.f + av[1]);
        o.z = 0.5f * s.z * (1.f + av[2]);
        o.w = 0.5f * s.w * (1.f + av[3]);
        *(float4*)&outB[(size_t)qrow * DDIM + d0] = o;
      }
    }
  }
}

extern "C" void kernel_launch(void* const* d_in, const int* in_sizes, int n_in,
                              void* d_out, int out_size, void* d_ws, size_t ws_size,
                              hipStream_t stream) {
  const float* seq  = (const float*)d_in[0];
  const float* fism = (const float*)d_in[1];
  float* out = (float*)d_out;
  if (ws_size >= 33554432ull) {
    _Float16* KF = (_Float16*)d_ws;
    _Float16* VF = KF + (size_t)NB * NKV * DDIM;
    prep<<<dim3(1024), dim3(256), 0, stream>>>(fism, KF, VF);
    gattn<<<dim3(512), dim3(256), 0, stream>>>(seq, KF, VF, out);
  } else {
    gattn_fb<<<dim3(256), dim3(512), 0, stream>>>(seq, fism, out);
  }
}

// Round 11
// 60.531 us; speedup vs baseline: 1.0331x; 1.0331x over previous
//
#include <hip/hip_runtime.h>
#include <hip/hip_bf16.h>
#include <math.h>

typedef _Float16 half8  __attribute__((ext_vector_type(8)));
typedef _Float16 half4v __attribute__((ext_vector_type(4)));
typedef __fp16   fp16x2 __attribute__((ext_vector_type(2)));
typedef float    f32x4  __attribute__((ext_vector_type(4)));
typedef float    f32x16 __attribute__((ext_vector_type(16)));
typedef int      i32x2v __attribute__((ext_vector_type(2)));

#define DDIM 128
#define LQ   512
#define NKV  2048
#define NB   32
#define NIT  16

union U32H2 { unsigned u; fp16x2 h; };
union PW    { unsigned u[4]; half8 h; };

// permlane32_swap(a,b) -> ([a_lo|b_lo], [a_hi|b_hi])
__device__ __forceinline__ float xmax64(float v) {
  i32x2v r = __builtin_amdgcn_permlane32_swap(__float_as_int(v), __float_as_int(v), false, false);
  return fmaxf(__int_as_float(r[0]), __int_as_float(r[1]));
}
__device__ __forceinline__ float xsum64(float v) {
  i32x2v r = __builtin_amdgcn_permlane32_swap(__float_as_int(v), __float_as_int(v), false, false);
  return __int_as_float(r[0]) + __int_as_float(r[1]);
}

__device__ __forceinline__ void dma16(const void* g, void* l) {
  __builtin_amdgcn_global_load_lds(
      (const __attribute__((address_space(1))) unsigned int*)g,
      (__attribute__((address_space(3))) unsigned int*)l, 16, 0, 0);
}

// ---------------- prep (r10-verified): fism f32 -> fragment-major KF / VF (f16) ----------------
// KF chunk (16KB): unit (ns*8+c)*64 + hi*32 + l31 holds K[ns*32+l31][c*16+hi*8 ..+8]
// VF chunk (16KB): unit (dt*4+kb)*64 + hi*32 + l31 holds V^T[dt*32+l31][kb*16+hi*8 ..+8]
__global__ __launch_bounds__(256)
void prep(const float* __restrict__ fism, _Float16* __restrict__ KF,
          _Float16* __restrict__ VF)
{
  __shared__ _Float16 T[64 * DDIM];
  const int tid = threadIdx.x;
  const int bb  = blockIdx.x >> 5;
  const int idx = blockIdx.x & 31;
  const int kv0 = idx * 64;
  {
    const int r  = tid >> 2;
    const int cq = tid & 3;
    const float* src = fism + ((size_t)(bb*NKV + kv0 + r) * DDIM + cq*32);
    float4 v[8];
    #pragma unroll
    for (int k = 0; k < 8; ++k) v[k] = ((const float4*)src)[k];
    _Float16 h[32];
    #pragma unroll
    for (int k = 0; k < 8; ++k) {
      h[4*k+0] = (_Float16)v[k].x; h[4*k+1] = (_Float16)v[k].y;
      h[4*k+2] = (_Float16)v[k].z; h[4*k+3] = (_Float16)v[k].w;
    }
    const size_t kfb = (size_t)(bb*32 + idx) * 8192;
    const int ns = r >> 5, l31r = r & 31;
    #pragma unroll
    for (int g = 0; g < 4; ++g) {
      const int c   = cq*2 + (g >> 1);
      const int hig = g & 1;
      const int unit = (ns*8 + c)*64 + hig*32 + l31r;
      *(half8*)&KF[kfb + (size_t)unit*8] = *(half8*)&h[(g>>1)*16 + hig*8];
    }
    #pragma unroll
    for (int j = 0; j < 32; ++j) {
      const int d = cq*32 + j;
      T[d*64 + (((r>>3) ^ (d&7))<<3) + (r&7)] = h[j];
    }
  }
  __syncthreads();
  {
    const size_t vfb = (size_t)(bb*32 + idx) * 8192;
    #pragma unroll
    for (int j = 0; j < 4; ++j) {
      const int u  = tid*4 + j;
      const int dt = u >> 8, kb = (u >> 6) & 3, l = u & 63;
      const int d  = dt*32 + (l & 31);
      const int kv8 = kb*2 + (l >> 5);
      *(half8*)&VF[vfb + (size_t)u*8] = *(half8*)&T[d*64 + ((kv8 ^ (d & 7)) << 3)];
    }
  }
}

// ---------------- main: double-buffered DMA, ONE barrier per iter ----------------
// POOL: K[kvh][buf] at (kvh*2+buf)*16384, 64KB; V at 65536 + (kvh*2+buf)*16384, 64KB.
__global__ __launch_bounds__(256, 1)
void gattn(const float* __restrict__ seq, const _Float16* __restrict__ KF,
           const _Float16* __restrict__ VF, float* __restrict__ out)
{
  __shared__ __align__(16) unsigned char POOL[131072];
  __shared__ float stats[2][32][4];

  const int tid  = threadIdx.x;
  const int lane = tid & 63;
  const int wv   = tid >> 6;      // 0..3
  const int qg   = wv & 1;        // q-group (32 rows)
  const int kvh  = wv >> 1;       // KV half
  const int l31  = lane & 31;
  const int hi   = lane >> 5;

  const int swz = (blockIdx.x & 7) * 32 + (blockIdx.x >> 3);
  const int b   = swz >> 3;
  const int qb  = (swz & 7) * 64;

  const float* seqB = seq + (size_t)b * LQ * DDIM;
  float*       outB = out + (size_t)b * LQ * DDIM;
  const _Float16* KFb = KF + (size_t)b * 32 * 8192;
  const _Float16* VFb = VF + (size_t)b * 32 * 8192;

  // ---- staging role: waves 0,1 stage K halves; waves 2,3 stage V halves ----
  const bool isK = (wv < 2);
  const int  hst = isK ? wv : (wv - 2);
  const _Float16* sbase = (isK ? KFb : VFb) + (size_t)hst * 16 * 8192;
  const int lgrp = (isK ? 0 : 65536) + hst * 32768;

  auto stage = [&](int tt) {
    const _Float16* s0 = sbase + (size_t)tt * 8192;
    const int l0 = lgrp + (tt & 1) * 16384;
    #pragma unroll
    for (int i = 0; i < 16; ++i)
      dma16(s0 + (size_t)(i*64 + lane)*8, &POOL[l0 + i*1024]);
  };

  stage(0);   // prologue DMA

  // ---- Q fragments in registers (B-frag: col=q=l31, k = c*16 + hi*8 + j) ----
  half8 qf[8];
  {
    const int qrow = qb + qg * 32 + l31;
    #pragma unroll
    for (int c = 0; c < 8; ++c) {
      const float* p = seqB + (size_t)qrow * DDIM + c * 16 + hi * 8;
      float4 a  = *(const float4*)p;
      float4 b2 = *(const float4*)(p + 4);
      half8 h;
      h[0]=(_Float16)a.x;  h[1]=(_Float16)a.y;  h[2]=(_Float16)a.z;  h[3]=(_Float16)a.w;
      h[4]=(_Float16)b2.x; h[5]=(_Float16)b2.y; h[6]=(_Float16)b2.z; h[7]=(_Float16)b2.w;
      qf[c] = h;
    }
  }

  f32x16 acc[4];
  #pragma unroll
  for (int dt = 0; dt < 4; ++dt)
    #pragma unroll
    for (int i = 0; i < 16; ++i) acc[dt][i] = 0.f;

  float m_run = -INFINITY, tmax = -INFINITY, S_run = 0.f;

  for (int t = 0; t < NIT; ++t) {
    __syncthreads();                 // single barrier: buf[t&1] landed; buf[t+1&1] free
    if (t + 1 < NIT) stage(t + 1);   // full iteration of compute covers this DMA

    const int kbB = kvh*32768 + (t & 1)*16384;
    const int vbB = 65536 + kvh*32768 + (t & 1)*16384;

    // ---- QK^T: A=K (m=kv), B=Q (col=q=l31). sv[ns]: row=kv, col=q ----
    f32x16 sv[2];
    __builtin_amdgcn_s_setprio(1);
    #pragma unroll
    for (int ns = 0; ns < 2; ++ns) {
      f32x16 x;
      #pragma unroll
      for (int i = 0; i < 16; ++i) x[i] = 0.f;
      #pragma unroll
      for (int c = 0; c < 8; ++c) {
        half8 ka = *(const half8*)&POOL[kbB + ((ns*8 + c)*64 + lane)*16];
        x = __builtin_amdgcn_mfma_f32_32x32x16_f16(ka, qf[c], x, 0, 0, 0);
      }
      sv[ns] = x;
    }
    __builtin_amdgcn_s_setprio(0);

    // ---- online power-softmax (lane-local, col=q) ----
    float mx[16];
    #pragma unroll
    for (int i = 0; i < 16; ++i) mx[i] = fmaxf(sv[0][i], sv[1][i]);
    #pragma unroll
    for (int st = 8; st > 0; st >>= 1)
      #pragma unroll
      for (int i = 0; i < st; ++i) mx[i] = fmaxf(mx[i], mx[i+st]);
    const float cmax = xmax64(mx[0]);
    tmax = fmaxf(tmax, cmax);
    if (__any(cmax > m_run + 8.f)) {
      const float mn = fmaxf(m_run, cmax);
      const float sc = __expf(m_run - mn);
      S_run *= sc;
      m_run = mn;
      #pragma unroll
      for (int dt = 0; dt < 4; ++dt) acc[dt] *= sc;
    }
    float ts[16];
    #pragma unroll
    for (int i = 0; i < 16; ++i) {
      const float p0 = __expf(sv[0][i] - m_run);
      const float p1 = __expf(sv[1][i] - m_run);
      sv[0][i] = p0; sv[1][i] = p1;
      ts[i] = p0 + p1;
    }
    #pragma unroll
    for (int st = 8; st > 0; st >>= 1)
      #pragma unroll
      for (int i = 0; i < st; ++i) ts[i] += ts[i+st];
    S_run += xsum64(ts[0]);

    // ---- P pack + permlane redistribute (T12, r7-verified) ----
    PW pw[4];
    #pragma unroll
    for (int nss = 0; nss < 2; ++nss)
      #pragma unroll
      for (int b0 = 0; b0 < 2; ++b0) {
        U32H2 t0, t1, t2, t3;
        t0.h = __builtin_amdgcn_cvt_pkrtz(sv[nss][8*b0+0], sv[nss][8*b0+1]);
        t1.h = __builtin_amdgcn_cvt_pkrtz(sv[nss][8*b0+2], sv[nss][8*b0+3]);
        t2.h = __builtin_amdgcn_cvt_pkrtz(sv[nss][8*b0+4], sv[nss][8*b0+5]);
        t3.h = __builtin_amdgcn_cvt_pkrtz(sv[nss][8*b0+6], sv[nss][8*b0+7]);
        i32x2v r0 = __builtin_amdgcn_permlane32_swap((int)t0.u, (int)t2.u, false, false);
        i32x2v r1 = __builtin_amdgcn_permlane32_swap((int)t1.u, (int)t3.u, false, false);
        const int kb = 2*nss + b0;
        pw[kb].u[0] = (unsigned)r0[0];
        pw[kb].u[1] = (unsigned)r1[0];
        pw[kb].u[2] = (unsigned)r0[1];
        pw[kb].u[3] = (unsigned)r1[1];
      }

    // ---- PV^T: A=V^T (m=d), B=P (col=q). acc[dt]: row=d, col=q ----
    __builtin_amdgcn_s_setprio(1);
    #pragma unroll
    for (int dt = 0; dt < 4; ++dt) {
      #pragma unroll
      for (int kb = 0; kb < 4; ++kb) {
        half8 vtf = *(const half8*)&POOL[vbB + ((dt*4 + kb)*64 + lane)*16];
        acc[dt] = __builtin_amdgcn_mfma_f32_32x32x16_f16(vtf, pw[kb].h, acc[dt], 0, 0, 0);
      }
    }
    __builtin_amdgcn_s_setprio(0);
  }

  __syncthreads();

  // ---- 2-way exact combine (kvh1 spills via LDS; kvh0 merges + epilogue) ----
  if (kvh == 1) {
    float* base = (float*)&POOL[qg * 16384];
    #pragma unroll
    for (int dt = 0; dt < 4; ++dt)
      #pragma unroll
      for (int rg = 0; rg < 4; ++rg) {
        const int j = dt*4 + rg;
        f32x4 v = {acc[dt][4*rg+0], acc[dt][4*rg+1], acc[dt][4*rg+2], acc[dt][4*rg+3]};
        *(f32x4*)&base[lane*64 + ((j ^ (lane & 15)) << 2)] = v;
      }
    if (lane < 32) {
      stats[qg][lane][0] = m_run;
      stats[qg][lane][1] = S_run;
      stats[qg][lane][2] = tmax;
    }
  }
  __syncthreads();

  if (kvh == 0) {
    const float m1 = stats[qg][l31][0];
    const float S1 = stats[qg][l31][1];
    const float t1 = stats[qg][l31][2];
    const float M2 = fmaxf(m_run, m1);
    const float e0 = __expf(m_run - M2), e1 = __expf(m1 - M2);
    const float S  = S_run * e0 + S1 * e1;
    const float T  = fmaxf(tmax, t1);
    const float fs = __expf(0.5f * (M2 - T)) * rsqrtf(S);

    const float* base = (const float*)&POOL[qg * 16384];
    const int qrw = qb + qg*32 + l31;
    #pragma unroll
    for (int dt = 0; dt < 4; ++dt) {
      #pragma unroll
      for (int rg = 0; rg < 4; ++rg) {
        const int j = dt*4 + rg;
        const f32x4 pj = *(const f32x4*)&base[lane*64 + ((j ^ (lane & 15)) << 2)];
        f32x4 av;
        #pragma unroll
        for (int i = 0; i < 4; ++i)
          av[i] = (acc[dt][4*rg+i] * e0 + pj[i] * e1) * fs;
        const int d0 = dt*32 + rg*8 + hi*4;
        const float4 s = *(const float4*)&seqB[(size_t)qrw * DDIM + d0];
        float4 o;
        o.x = 0.5f * s.x * (1.f + av[0]);
        o.y = 0.5f * s.y * (1.f + av[1]);
        o.z = 0.5f * s.z * (1.f + av[2]);
        o.w = 0.5f * s.w * (1.f + av[3]);
        *(float4*)&outB[(size_t)qrw * DDIM + d0] = o;
      }
    }
  }
}

// ---------------- fallback (r7, proven): used if ws too small ----------------
__global__ __launch_bounds__(512, 2)
void gattn_fb(const float* __restrict__ seq, const float* __restrict__ fism,
              float* __restrict__ out)
{
  const int tid  = threadIdx.x;
  const int lane = tid & 63;
  const int wv   = tid >> 6;
  const int wq   = wv & 1;
  const int kvq  = wv >> 1;
  const int l31  = lane & 31;
  const int hi   = lane >> 5;

  const int swz = (blockIdx.x & 7) * 32 + (blockIdx.x >> 3);
  const int b   = swz >> 3;
  const int qb  = (swz & 7) * 64;

  const float* seqB = seq  + (size_t)b * LQ * DDIM;
  const float* fisB = fism + (size_t)b * NKV * DDIM;
  float*       outB = out  + (size_t)b * LQ * DDIM;

  __shared__ _Float16 Ksh[4][64 * DDIM];
  __shared__ _Float16 VTsh[4][(DDIM/2) * 128];
  __shared__ float    stats[4][2][32][3];

  half8 qf[8];
  {
    const int qrow = qb + wq * 32 + l31;
    #pragma unroll
    for (int c = 0; c < 8; ++c) {
      const float* p = seqB + (size_t)qrow * DDIM + c * 16 + hi * 8;
      float4 a  = *(const float4*)p;
      float4 b2 = *(const float4*)(p + 4);
      half8 h;
      h[0]=(_Float16)a.x;  h[1]=(_Float16)a.y;  h[2]=(_Float16)a.z;  h[3]=(_Float16)a.w;
      h[4]=(_Float16)b2.x; h[5]=(_Float16)b2.y; h[6]=(_Float16)b2.z; h[7]=(_Float16)b2.w;
      qf[c] = h;
    }
  }

  const int sp   = tid >> 3;
  const int dgrp = tid & 7;
  const int qstg = sp >> 4;
  const int spc  = sp & 15;

  f32x16 acc[4];
  #pragma unroll
  for (int dt = 0; dt < 4; ++dt)
    #pragma unroll
    for (int i = 0; i < 16; ++i) acc[dt][i] = 0.f;

  float m_run = -INFINITY, tmax = -INFINITY, S_run = 0.f;

  auto write_stage = [&](const float4* v) {
    #pragma unroll
    for (int r = 0; r < 4; ++r) {
      const int row = 4*spc + r;
      #pragma unroll
      for (int hh = 0; hh < 2; ++hh) {
        const float4 x = v[r*4 + hh*2];
        const float4 y = v[r*4 + hh*2 + 1];
        half8 h;
        h[0]=(_Float16)x.x; h[1]=(_Float16)x.y; h[2]=(_Float16)x.z; h[3]=(_Float16)x.w;
        h[4]=(_Float16)y.x; h[5]=(_Float16)y.y; h[6]=(_Float16)y.z; h[7]=(_Float16)y.w;
        const int idx = row*DDIM + ((dgrp*16 + hh*8) ^ (8*(row & 15)));
        *(half8*)&Ksh[qstg][idx] = h;
      }
    }
    #pragma unroll
    for (int k = 0; k < 16; ++k) {
      const int d = dgrp*16 + k;
      const int dRow = d >> 1, dSub = d & 1;
      half4v pk;
      #pragma unroll
      for (int r = 0; r < 4; ++r)
        pk[r] = (_Float16)(((const float*)&v[r*4 + (k>>2)])[k&3]);
      const int idx = dRow*128 + ((dSub*64 + 4*spc) ^ (8*(dRow & 15)));
      *(half4v*)&VTsh[qstg][idx] = pk;
    }
  };

  auto load_glb = [&](float4* v, int t) {
    const float* src = fisB + (size_t)(qstg*(NKV/4) + t*64) * DDIM;
    #pragma unroll
    for (int r = 0; r < 4; ++r)
      #pragma unroll
      for (int k = 0; k < 4; ++k)
        v[r*4+k] = *(const float4*)(src + (size_t)(4*spc + r)*DDIM + dgrp*16 + k*4);
  };

  {
    float4 stg[16];
    load_glb(stg, 0);
    write_stage(stg);
  }

  for (int t = 0; t < 8; ++t) {
    __syncthreads();
    float4 nxt[16];
    const bool have = (t + 1 < 8);
    if (have) load_glb(nxt, t + 1);

    f32x16 sv[2];
    #pragma unroll
    for (int nss = 0; nss < 2; ++nss) {
      f32x16 x;
      #pragma unroll
      for (int i = 0; i < 16; ++i) x[i] = 0.f;
      const int row = nss*32 + l31;
      const int sw  = 8*(row & 15);
      #pragma unroll
      for (int c = 0; c < 8; ++c) {
        const int idx = row*DDIM + ((c*16 + hi*8) ^ sw);
        half8 kf = *(const half8*)&Ksh[kvq][idx];
        x = __builtin_amdgcn_mfma_f32_32x32x16_f16(kf, qf[c], x, 0, 0, 0);
      }
      sv[nss] = x;
    }

    float mx[16];
    #pragma unroll
    for (int i = 0; i < 16; ++i) mx[i] = fmaxf(sv[0][i], sv[1][i]);
    #pragma unroll
    for (int st = 8; st > 0; st >>= 1)
      #pragma unroll
      for (int i = 0; i < st; ++i) mx[i] = fmaxf(mx[i], mx[i+st]);
    const float cmax = xmax64(mx[0]);
    tmax = fmaxf(tmax, cmax);
    if (__any(cmax > m_run + 8.f)) {
      const float mn = fmaxf(m_run, cmax);
      const float sc = __expf(m_run - mn);
      S_run *= sc;
      m_run = mn;
      #pragma unroll
      for (int dt = 0; dt < 4; ++dt) acc[dt] *= sc;
    }
    float ts[16];
    #pragma unroll
    for (int i = 0; i < 16; ++i) {
      const float p0 = __expf(sv[0][i] - m_run);
      const float p1 = __expf(sv[1][i] - m_run);
      sv[0][i] = p0; sv[1][i] = p1;
      ts[i] = p0 + p1;
    }
    #pragma unroll
    for (int st = 8; st > 0; st >>= 1)
      #pragma unroll
      for (int i = 0; i < st; ++i) ts[i] += ts[i+st];
    S_run += xsum64(ts[0]);

    PW pw[4];
    #pragma unroll
    for (int nss = 0; nss < 2; ++nss)
      #pragma unroll
      for (int b0 = 0; b0 < 2; ++b0) {
        U32H2 t0, t1, t2, t3;
        t0.h = __builtin_amdgcn_cvt_pkrtz(sv[nss][8*b0+0], sv[nss][8*b0+1]);
        t1.h = __builtin_amdgcn_cvt_pkrtz(sv[nss][8*b0+2], sv[nss][8*b0+3]);
        t2.h = __builtin_amdgcn_cvt_pkrtz(sv[nss][8*b0+4], sv[nss][8*b0+5]);
        t3.h = __builtin_amdgcn_cvt_pkrtz(sv[nss][8*b0+6], sv[nss][8*b0+7]);
        i32x2v r0 = __builtin_amdgcn_permlane32_swap((int)t0.u, (int)t2.u, false, false);
        i32x2v r1 = __builtin_amdgcn_permlane32_swap((int)t1.u, (int)t3.u, false, false);
        const int kb = 2*nss + b0;
        pw[kb].u[0] = (unsigned)r0[0];
        pw[kb].u[1] = (unsigned)r1[0];
        pw[kb].u[2] = (unsigned)r0[1];
        pw[kb].u[3] = (unsigned)r1[1];
      }

    #pragma unroll
    for (int dt = 0; dt < 4; ++dt) {
      const int d    = dt*32 + l31;
      const int dRow = d >> 1, dSub = d & 1;
      const int sw   = 8*(dRow & 15);
      #pragma unroll
      for (int kb = 0; kb < 4; ++kb) {
        const int idx = dRow*128 + ((dSub*64 + kb*16 + hi*8) ^ sw);
        half8 vtf = *(const half8*)&VTsh[kvq][idx];
        acc[dt] = __builtin_amdgcn_mfma_f32_32x32x16_f16(vtf, pw[kb].h, acc[dt], 0, 0, 0);
      }
    }

    __syncthreads();
    if (have) write_stage(nxt);
  }

  __syncthreads();

  float* Kf  = (float*)&Ksh[0][0];
  float* VTf = (float*)&VTsh[0][0];
  if (kvq != 0) {
    const int rgn = (kvq - 1) * 2 + wq;
    float* base = (rgn < 4) ? (Kf + rgn * 4096) : (VTf + (rgn - 4) * 4096);
    #pragma unroll
    for (int dt = 0; dt < 4; ++dt)
      #pragma unroll
      for (int rg = 0; rg < 4; ++rg) {
        f32x4 v = {acc[dt][4*rg+0], acc[dt][4*rg+1], acc[dt][4*rg+2], acc[dt][4*rg+3]};
        *(f32x4*)&base[lane*64 + (((dt*4+rg) ^ (lane & 15)) * 4)] = v;
      }
    if (lane < 32) {
      stats[kvq][wq][lane][0] = m_run;
      stats[kvq][wq][lane][1] = S_run;
      stats[kvq][wq][lane][2] = tmax;
    }
  }
  __syncthreads();

  if (kvq == 0) {
    float mj[4], Sj[4], tj[4];
    mj[0] = m_run; Sj[0] = S_run; tj[0] = tmax;
    #pragma unroll
    for (int j = 1; j < 4; ++j) {
      mj[j] = stats[j][wq][l31][0];
      Sj[j] = stats[j][wq][l31][1];
      tj[j] = stats[j][wq][l31][2];
    }
    const float M = fmaxf(fmaxf(tj[0], tj[1]), fmaxf(tj[2], tj[3]));
    float fj[4], den = 0.f;
    #pragma unroll
    for (int j = 0; j < 4; ++j) { fj[j] = __expf(mj[j] - M); den += fj[j] * Sj[j]; }
    const float rs = rsqrtf(den);
    #pragma unroll
    for (int j = 0; j < 4; ++j) fj[j] *= rs;

    const int qrow = qb + wq*32 + l31;
    #pragma unroll
    for (int dt = 0; dt < 4; ++dt) {
      #pragma unroll
      for (int rg = 0; rg < 4; ++rg) {
        f32x4 av = {acc[dt][4*rg+0], acc[dt][4*rg+1], acc[dt][4*rg+2], acc[dt][4*rg+3]};
        av *= fj[0];
        #pragma unroll
        for (int j = 1; j < 4; ++j) {
          const int rgn = (j - 1) * 2 + wq;
          const float* base = (rgn < 4) ? (Kf + rgn * 4096) : (VTf + (rgn - 4) * 4096);
          const f32x4 pj = *(const f32x4*)&base[lane*64 + (((dt*4+rg) ^ (lane & 15)) * 4)];
          av += pj * fj[j];
        }
        const int d0 = dt*32 + rg*8 + hi*4;
        const float4 s = *(const float4*)&seqB[(size_t)qrow * DDIM + d0];
        float4 o;
        o.x = 0.5f * s.x * (1.f + av[0]);
        o.y = 0.5f * s.y * (1.f + av[1]);
        o.z = 0.5f * s.z * (1.f + av[2]);
        o.w = 0.5f * s.w * (1.f + av[3]);
        *(float4*)&outB[(size_t)qrow * DDIM + d0] = o;
      }
    }
  }
}

extern "C" void kernel_launch(void* const* d_in, const int* in_sizes, int n_in,
                              void* d_out, int out_size, void* d_ws, size_t ws_size,
                              hipStream_t stream) {
  const float* seq  = (const float*)d_in[0];
  const float* fism = (const float*)d_in[1];
  float* out = (float*)d_out;
  if (ws_size >= 33554432ull) {
    _Float16* KF = (_Float16*)d_ws;
    _Float16* VF = KF + (size_t)NB * NKV * DDIM;
    prep<<<dim3(1024), dim3(256), 0, stream>>>(fism, KF, VF);
    gattn<<<dim3(256), dim3(256), 0, stream>>>(seq, KF, VF, out);
  } else {
    gattn_fb<<<dim3(256), dim3(512), 0, stream>>>(seq, fism, out);
  }
}